// Round 1
// baseline (150.284 us; speedup 1.0000x reference)
//
#include <hip/hip_runtime.h>
#include <math.h>

#define N_ 128
#define D_ 2048
#define C_ 256
#define K_ 8192

// logits: N_*(K_+1) floats at out[0]
// labels: N_ int32 at out[N_*(K_+1)]
// f_logit: N_*C_ floats at out[N_*(K_+1)+N_]
#define LBL_OFF  (N_ * (K_ + 1))
#define FLOG_OFF (N_ * (K_ + 1) + N_)

__device__ __forceinline__ float fast_exp2(float x) {
#if __has_builtin(__builtin_amdgcn_exp2f)
  return __builtin_amdgcn_exp2f(x);   // v_exp_f32
#else
  return exp2f(x);
#endif
}

__device__ __forceinline__ float fast_log2(float x) {
#if __has_builtin(__builtin_amdgcn_logf)
  return __builtin_amdgcn_logf(x);    // v_log_f32 (= log2)
#else
  return __log2f(x);
#endif
}

__constant__ const float kLog2e  = 1.4426950408889634f;
__constant__ const float kLn2OvT = 9.902102579427789f;   // ln(2)/0.07
__constant__ const float kInvT   = 14.285714285714286f;  // 1/0.07

// ---------------------------------------------------------------------------
// Kernel 1: zero the penult accumulator in ws + column norms of queue_logit.
// rnorm[k] = log2(e) / max(||q[:,k]||, 1e-12)  (log2e folded for exp2 use)
// grid 32 x 256
// ---------------------------------------------------------------------------
__global__ __launch_bounds__(256) void k_prep(const float* __restrict__ q,
                                              float* __restrict__ pen,
                                              float* __restrict__ rnorm) {
  const int t = blockIdx.x * 256 + threadIdx.x;  // 0..8191
  pen[t] = 0.f;
  pen[t + 8192] = 0.f;
  pen[t + 16384] = 0.f;
  pen[t + 24576] = 0.f;
  float s = 0.f;
#pragma unroll 8
  for (int c = 0; c < C_; ++c) {
    float v = q[(size_t)c * K_ + t];
    s = fmaf(v, v, s);
  }
  rnorm[t] = kLog2e / fmaxf(sqrtf(s), 1e-12f);
}

// ---------------------------------------------------------------------------
// Kernel 2: penult = img @ W_f  (split-K over D, fp32 atomics into ws).
// grid 128 (8 n-tiles x 16 d-chunks), block 256 (= all C columns)
// ---------------------------------------------------------------------------
__global__ __launch_bounds__(256) void k_gemm1(const float* __restrict__ img,
                                               const float* __restrict__ Wf,
                                               float* __restrict__ pen) {
  const int n0 = (blockIdx.x >> 4) * 16;
  const int d0 = (blockIdx.x & 15) * 128;
  const int thr = threadIdx.x;
  __shared__ float imgT[128][20];  // [d_local][n_local], pad 16->20 (16B aligned)

#pragma unroll
  for (int l = 0; l < 8; ++l) {
    int idx = thr + l * 256;       // 0..2047
    int dl = idx & 127;
    int nl = idx >> 7;
    imgT[dl][nl] = img[(size_t)(n0 + nl) * D_ + d0 + dl];
  }
  __syncthreads();

  float acc[16];
#pragma unroll
  for (int i = 0; i < 16; ++i) acc[i] = 0.f;

  for (int dl = 0; dl < 128; ++dl) {
    float w = Wf[(size_t)(d0 + dl) * C_ + thr];
    const float4* ip = (const float4*)&imgT[dl][0];
    float4 a0 = ip[0], a1 = ip[1], a2 = ip[2], a3 = ip[3];
    acc[0]  = fmaf(a0.x, w, acc[0]);  acc[1]  = fmaf(a0.y, w, acc[1]);
    acc[2]  = fmaf(a0.z, w, acc[2]);  acc[3]  = fmaf(a0.w, w, acc[3]);
    acc[4]  = fmaf(a1.x, w, acc[4]);  acc[5]  = fmaf(a1.y, w, acc[5]);
    acc[6]  = fmaf(a1.z, w, acc[6]);  acc[7]  = fmaf(a1.w, w, acc[7]);
    acc[8]  = fmaf(a2.x, w, acc[8]);  acc[9]  = fmaf(a2.y, w, acc[9]);
    acc[10] = fmaf(a2.z, w, acc[10]); acc[11] = fmaf(a2.w, w, acc[11]);
    acc[12] = fmaf(a3.x, w, acc[12]); acc[13] = fmaf(a3.y, w, acc[13]);
    acc[14] = fmaf(a3.z, w, acc[14]); acc[15] = fmaf(a3.w, w, acc[15]);
  }
#pragma unroll
  for (int i = 0; i < 16; ++i)
    atomicAdd(&pen[(size_t)(n0 + i) * C_ + thr], acc[i]);
}

// ---------------------------------------------------------------------------
// Kernel 3: f_logit = (penult+b_f) @ W_c + b_c ; row-l2norm ; l_pos ; labels.
// grid 128 (one block per row n), block 256 (= C columns)
// ---------------------------------------------------------------------------
__global__ __launch_bounds__(256) void k_head(const float* __restrict__ pen_in,
                                              const float* __restrict__ bf,
                                              const float* __restrict__ Wc,
                                              const float* __restrict__ bc,
                                              const float* __restrict__ dist,
                                              float* __restrict__ out) {
  const int n = blockIdx.x;
  const int c = threadIdx.x;
  __shared__ float pen[256];
  __shared__ float red1[4], red2[4];

  pen[c] = pen_in[(size_t)n * C_ + c] + bf[c];
  __syncthreads();

  float acc = bc[c];
#pragma unroll 8
  for (int j = 0; j < C_; ++j)
    acc = fmaf(pen[j], Wc[(size_t)j * C_ + c], acc);

  out[FLOG_OFF + (size_t)n * C_ + c] = acc;  // f_logit output

  // row sum of squares -> norm
  float ss = acc * acc;
#pragma unroll
  for (int off = 32; off >= 1; off >>= 1) ss += __shfl_xor(ss, off, 64);
  const int wave = c >> 6, lane = c & 63;
  if (lane == 0) red1[wave] = ss;
  __syncthreads();
  float sumsq = red1[0] + red1[1] + red1[2] + red1[3];
  float rn = 1.f / fmaxf(sqrtf(sumsq), 1e-12f);

  // logsumexp over c of dist*prob (scores bounded in [-1,1]: no max-shift)
  float s = dist[(size_t)n * C_ + c] * acc * rn;
  float e = fast_exp2(s * kLog2e);
#pragma unroll
  for (int off = 32; off >= 1; off >>= 1) e += __shfl_xor(e, off, 64);
  if (lane == 0) red2[wave] = e;
  __syncthreads();
  if (c == 0) {
    float sum = red2[0] + red2[1] + red2[2] + red2[3];
    out[(size_t)n * (K_ + 1)] = fast_log2(sum) * kLn2OvT;  // ln(sum)/T
    ((int*)out)[LBL_OFF + n] = 0;                          // label
  }
}

// ---------------------------------------------------------------------------
// Kernel 4 (the hot one): l_neg[n,k] = ln(sum_c exp(dist[n,c]*buf[c,k]))/T.
// grid (32 k-tiles, 16 n-tiles of 8), block 256 (thread = one k).
// Inner loop per c: 1 coalesced global load of q, broadcast LDS reads of
// dist, 8x (v_mul + v_exp_f32 + v_add). Trans-pipe bound.
// ---------------------------------------------------------------------------
__global__ __launch_bounds__(256, 2) void k_lneg(const float* __restrict__ q,
                                                 const float* __restrict__ dist,
                                                 const float* __restrict__ rnorm,
                                                 float* __restrict__ out) {
  const int thr = threadIdx.x;
  const int k = blockIdx.x * 256 + thr;
  const int n0 = blockIdx.y * 8;
  __shared__ float distT[256][8];  // [c][n_local]

#pragma unroll
  for (int l = 0; l < 8; ++l) {
    int idx = thr + l * 256;                    // 0..2047, coalesced global
    distT[idx & 255][idx >> 8] = dist[(size_t)n0 * C_ + idx];
  }
  __syncthreads();

  const float rn = rnorm[k];  // = log2(e)/||q[:,k]||
  float acc[8];
#pragma unroll
  for (int i = 0; i < 8; ++i) acc[i] = 0.f;

#pragma unroll 4
  for (int c = 0; c < C_; ++c) {
    float b = q[(size_t)c * K_ + k] * rn;       // coalesced; L2-resident
    float4 da = *(const float4*)&distT[c][0];   // wave-uniform broadcast
    float4 db = *(const float4*)&distT[c][4];
    acc[0] += fast_exp2(da.x * b);
    acc[1] += fast_exp2(da.y * b);
    acc[2] += fast_exp2(da.z * b);
    acc[3] += fast_exp2(da.w * b);
    acc[4] += fast_exp2(db.x * b);
    acc[5] += fast_exp2(db.y * b);
    acc[6] += fast_exp2(db.z * b);
    acc[7] += fast_exp2(db.w * b);
  }

#pragma unroll
  for (int i = 0; i < 8; ++i)
    out[(size_t)(n0 + i) * (K_ + 1) + 1 + k] = fast_log2(acc[i]) * kLn2OvT;
}

extern "C" void kernel_launch(void* const* d_in, const int* in_sizes, int n_in,
                              void* d_out, int out_size, void* d_ws, size_t ws_size,
                              hipStream_t stream) {
  const float* img  = (const float*)d_in[0];
  const float* Wf   = (const float*)d_in[1];
  const float* bf   = (const float*)d_in[2];
  const float* Wc   = (const float*)d_in[3];
  const float* bc   = (const float*)d_in[4];
  const float* dist = (const float*)d_in[5];
  const float* q    = (const float*)d_in[6];
  float* out = (float*)d_out;

  float* pen   = (float*)d_ws;        // N_*C_ = 32768 floats
  float* rnorm = pen + N_ * C_;       // K_ = 8192 floats

  hipLaunchKernelGGL(k_prep,  dim3(32),     dim3(256), 0, stream, q, pen, rnorm);
  hipLaunchKernelGGL(k_gemm1, dim3(128),    dim3(256), 0, stream, img, Wf, pen);
  hipLaunchKernelGGL(k_head,  dim3(128),    dim3(256), 0, stream, pen, bf, Wc, bc, dist, out);
  hipLaunchKernelGGL(k_lneg,  dim3(32, 16), dim3(256), 0, stream, q, dist, rnorm, out);
}

// Round 2
// 128.933 us; speedup vs baseline: 1.1656x; 1.1656x over previous
//
#include <hip/hip_runtime.h>
#include <math.h>

#define N_ 128
#define D_ 2048
#define C_ 256
#define K_ 8192

// out layout: logits [N_][K_+1] | labels [N_] (int32) | f_logit [N_][C_]
#define LBL_OFF  (N_ * (K_ + 1))
#define FLOG_OFF (N_ * (K_ + 1) + N_)

__device__ __forceinline__ float fast_exp2(float x) {
  return __builtin_amdgcn_exp2f(x);   // v_exp_f32
}
__device__ __forceinline__ float fast_log2(float x) {
  return __builtin_amdgcn_logf(x);    // v_log_f32 (log2)
}

constexpr float kLog2e  = 1.4426950408889634f;
constexpr float kLn2OvT = 9.902102579427789f;   // ln(2)/0.07

// ws layout:
//   penp: [32][N_][C_]  gemm1 partials   (1,048,576 floats, 4 MB)
//   ssqp: [8][K_]       colnorm partials (65,536 floats, 256 KB)

// ---------------------------------------------------------------------------
// Kernel 1: partial column sum-of-squares of queue_logit.
// grid 256 = 32 k-tiles x 8 c-chunks of 32. Full unroll -> 32 loads in
// flight per thread; 1024 waves cover the chip. HBM-bound: ~6 us for 32 MB.
// ---------------------------------------------------------------------------
__global__ __launch_bounds__(256) void k_prep(const float* __restrict__ q,
                                              float* __restrict__ ssqp) {
  const int kt = blockIdx.x & 31;
  const int cc = blockIdx.x >> 5;
  const int k = kt * 256 + threadIdx.x;
  const float* qp = q + (size_t)(cc * 32) * K_ + k;
  float s = 0.f;
#pragma unroll
  for (int j = 0; j < 32; ++j) {
    float v = qp[(size_t)j * K_];
    s = fmaf(v, v, s);
  }
  ssqp[(size_t)cc * K_ + k] = s;
}

// ---------------------------------------------------------------------------
// Kernel 2: penult partials = img @ W_f (split-K over D, 32 chunks of 64).
// grid 256 (8 n-tiles x 32 d-chunks), block 256 (= C columns). No atomics:
// each block stores its own partial tile; k_head reduces.
// ---------------------------------------------------------------------------
__global__ __launch_bounds__(256) void k_gemm1(const float* __restrict__ img,
                                               const float* __restrict__ Wf,
                                               float* __restrict__ penp) {
  const int nt = blockIdx.x >> 5;
  const int ch = blockIdx.x & 31;
  const int n0 = nt * 16, d0 = ch * 64;
  const int thr = threadIdx.x;
  __shared__ float imgT[64][20];  // [d_local][n_local], 80B rows (16B aligned)

#pragma unroll
  for (int l = 0; l < 4; ++l) {
    int idx = thr + l * 256;     // 0..1023
    int dl = idx & 63, nl = idx >> 6;
    imgT[dl][nl] = img[(size_t)(n0 + nl) * D_ + d0 + dl];
  }
  __syncthreads();

  float acc[16];
#pragma unroll
  for (int i = 0; i < 16; ++i) acc[i] = 0.f;

  const float* wp = Wf + (size_t)d0 * C_ + thr;
  float wpre = wp[0];
  for (int dl = 0; dl < 64; ++dl) {
    float w = wpre;
    wpre = wp[(size_t)((dl + 1) & 63) * C_];  // prefetch next row (wraps; dead on last)
    const float4* ip = (const float4*)&imgT[dl][0];  // broadcast reads
    float4 a0 = ip[0], a1 = ip[1], a2 = ip[2], a3 = ip[3];
    acc[0]  = fmaf(a0.x, w, acc[0]);  acc[1]  = fmaf(a0.y, w, acc[1]);
    acc[2]  = fmaf(a0.z, w, acc[2]);  acc[3]  = fmaf(a0.w, w, acc[3]);
    acc[4]  = fmaf(a1.x, w, acc[4]);  acc[5]  = fmaf(a1.y, w, acc[5]);
    acc[6]  = fmaf(a1.z, w, acc[6]);  acc[7]  = fmaf(a1.w, w, acc[7]);
    acc[8]  = fmaf(a2.x, w, acc[8]);  acc[9]  = fmaf(a2.y, w, acc[9]);
    acc[10] = fmaf(a2.z, w, acc[10]); acc[11] = fmaf(a2.w, w, acc[11]);
    acc[12] = fmaf(a3.x, w, acc[12]); acc[13] = fmaf(a3.y, w, acc[13]);
    acc[14] = fmaf(a3.z, w, acc[14]); acc[15] = fmaf(a3.w, w, acc[15]);
  }

  float* o = penp + ((size_t)ch * N_ + n0) * C_ + thr;
#pragma unroll
  for (int i = 0; i < 16; ++i) o[(size_t)i * C_] = acc[i];
}

// ---------------------------------------------------------------------------
// Kernel 3: reduce pen partials; f_logit = (pen+b_f) @ W_c + b_c; row-l2norm;
// l_pos; labels. grid 128 (block per row), block 256 (= C columns).
// ---------------------------------------------------------------------------
__global__ __launch_bounds__(256) void k_head(const float* __restrict__ penp,
                                              const float* __restrict__ bf,
                                              const float* __restrict__ Wc,
                                              const float* __restrict__ bc,
                                              const float* __restrict__ dist,
                                              float* __restrict__ out) {
  const int n = blockIdx.x;
  const int c = threadIdx.x;
  __shared__ float pen[256];
  __shared__ float red1[4], red2[4];

  float p = 0.f;
#pragma unroll
  for (int ch = 0; ch < 32; ++ch)        // 32 coalesced loads, all in flight
    p += penp[((size_t)ch * N_ + n) * C_ + c];
  pen[c] = p + bf[c];
  __syncthreads();

  float acc = bc[c];
#pragma unroll 16
  for (int j = 0; j < C_; ++j)
    acc = fmaf(pen[j], Wc[(size_t)j * C_ + c], acc);

  out[FLOG_OFF + (size_t)n * C_ + c] = acc;  // f_logit

  float ss = acc * acc;
#pragma unroll
  for (int off = 32; off >= 1; off >>= 1) ss += __shfl_xor(ss, off, 64);
  const int wave = c >> 6, lane = c & 63;
  if (lane == 0) red1[wave] = ss;
  __syncthreads();
  float sumsq = red1[0] + red1[1] + red1[2] + red1[3];
  float rn = 1.f / fmaxf(sqrtf(sumsq), 1e-12f);

  // scores bounded in [-1,1] -> no max-shift needed
  float s = dist[(size_t)n * C_ + c] * acc * rn;
  float e = fast_exp2(s * kLog2e);
#pragma unroll
  for (int off = 32; off >= 1; off >>= 1) e += __shfl_xor(e, off, 64);
  if (lane == 0) red2[wave] = e;
  __syncthreads();
  if (c == 0) {
    float sum = red2[0] + red2[1] + red2[2] + red2[3];
    out[(size_t)n * (K_ + 1)] = fast_log2(sum) * kLn2OvT;  // l_pos = ln(sum)/T
    ((int*)out)[LBL_OFF + n] = 0;                          // label
  }
}

// ---------------------------------------------------------------------------
// Kernel 4 (hot): l_neg[n,k] = ln(sum_c exp(dist[n,c]*q[c,k]/||q_k||))/T.
// grid (32 k-tiles, 16 n-tiles of 8), block 256 (thread = one k).
// Register software-pipeline: prefetch next 8 q values while 64 exps
// (512 trans cycles/wave) retire -> trans-pipe bound (~14 us floor).
// ---------------------------------------------------------------------------
__global__ __launch_bounds__(256, 2) void k_lneg(const float* __restrict__ q,
                                                 const float* __restrict__ dist,
                                                 const float* __restrict__ ssqp,
                                                 float* __restrict__ out) {
  const int thr = threadIdx.x;
  const int k = blockIdx.x * 256 + thr;
  const int n0 = blockIdx.y * 8;
  __shared__ float distT[256][8];  // [c][n_local], rows 32B

#pragma unroll
  for (int l = 0; l < 8; ++l) {
    int idx = thr + l * 256;                    // coalesced
    distT[idx & 255][idx >> 8] = dist[(size_t)n0 * C_ + idx];
  }

  // finalize column rnorm from the 8 partials (loads overlap LDS staging)
  float ssq = 0.f;
#pragma unroll
  for (int cc = 0; cc < 8; ++cc) ssq += ssqp[(size_t)cc * K_ + k];
  const float rn = kLog2e / fmaxf(sqrtf(ssq), 1e-12f);
  __syncthreads();

  float acc[8];
#pragma unroll
  for (int i = 0; i < 8; ++i) acc[i] = 0.f;

  const float* qp = q + k;
  float pre[8], cur[8];
#pragma unroll
  for (int i = 0; i < 8; ++i) pre[i] = qp[(size_t)i * K_];

  for (int c = 0; c < C_; c += 8) {
#pragma unroll
    for (int i = 0; i < 8; ++i) cur[i] = pre[i];
    // branchless prefetch (last iteration re-reads row 255 harmlessly)
#pragma unroll
    for (int i = 0; i < 8; ++i) {
      int cn = c + 8 + i; cn = cn > 255 ? 255 : cn;
      pre[i] = qp[(size_t)cn * K_];
    }
#pragma unroll
    for (int i = 0; i < 8; ++i) {
      float b = cur[i] * rn;
      float4 da = *(const float4*)&distT[c + i][0];   // broadcast
      float4 db = *(const float4*)&distT[c + i][4];
      acc[0] += fast_exp2(da.x * b);
      acc[1] += fast_exp2(da.y * b);
      acc[2] += fast_exp2(da.z * b);
      acc[3] += fast_exp2(da.w * b);
      acc[4] += fast_exp2(db.x * b);
      acc[5] += fast_exp2(db.y * b);
      acc[6] += fast_exp2(db.z * b);
      acc[7] += fast_exp2(db.w * b);
    }
  }

#pragma unroll
  for (int i = 0; i < 8; ++i)
    out[(size_t)(n0 + i) * (K_ + 1) + 1 + k] = fast_log2(acc[i]) * kLn2OvT;
}

extern "C" void kernel_launch(void* const* d_in, const int* in_sizes, int n_in,
                              void* d_out, int out_size, void* d_ws, size_t ws_size,
                              hipStream_t stream) {
  const float* img  = (const float*)d_in[0];
  const float* Wf   = (const float*)d_in[1];
  const float* bf   = (const float*)d_in[2];
  const float* Wc   = (const float*)d_in[3];
  const float* bc   = (const float*)d_in[4];
  const float* dist = (const float*)d_in[5];
  const float* q    = (const float*)d_in[6];
  float* out = (float*)d_out;

  float* penp = (float*)d_ws;             // 32*N_*C_ floats
  float* ssqp = penp + 32 * N_ * C_;      // 8*K_ floats

  hipLaunchKernelGGL(k_prep,  dim3(256),    dim3(256), 0, stream, q, ssqp);
  hipLaunchKernelGGL(k_gemm1, dim3(256),    dim3(256), 0, stream, img, Wf, penp);
  hipLaunchKernelGGL(k_head,  dim3(128),    dim3(256), 0, stream, penp, bf, Wc, bc, dist, out);
  hipLaunchKernelGGL(k_lneg,  dim3(32, 16), dim3(256), 0, stream, q, dist, ssqp, out);
}